// Round 1
// baseline (3923.503 us; speedup 1.0000x reference)
//
#include <hip/hip_runtime.h>

#define N_ENEMY 4000000
#define N_GUN   1000000
#define N_EDGES 16000000
#define HID     64
#define OUTD    8

// ---- Fold W_l@W_fc (4x8), W_r@W_fc (8), b_l@W_fc + b_fc (8) into P[48] ----
__global__ void prep_params(const float* __restrict__ W_l, const float* __restrict__ b_l,
                            const float* __restrict__ W_r, const float* __restrict__ W_fc,
                            const float* __restrict__ b_fc, float* __restrict__ P) {
    int o = threadIdx.x;
    if (o < OUTD) {
        float a0 = 0.f, a1 = 0.f, a2 = 0.f, a3 = 0.f, r = 0.f, c = 0.f;
        for (int h = 0; h < HID; ++h) {
            float w = W_fc[h * OUTD + o];
            a0 += W_l[0 * HID + h] * w;
            a1 += W_l[1 * HID + h] * w;
            a2 += W_l[2 * HID + h] * w;
            a3 += W_l[3 * HID + h] * w;
            r  += W_r[h] * w;
            c  += b_l[h] * w;
        }
        P[0 * OUTD + o] = a0;
        P[1 * OUTD + o] = a1;
        P[2 * OUTD + o] = a2;
        P[3 * OUTD + o] = a3;
        P[4 * OUTD + o] = r;
        P[5 * OUTD + o] = c + b_fc[o];
    }
}

// ---- Scatter-add: 4 edges per thread, int4/float4 vectorized ----
__global__ void edge_kernel(const int4* __restrict__ esrc4, const int4* __restrict__ edst4,
                            const float4* __restrict__ xe, float* __restrict__ summed,
                            float* __restrict__ counts) {
    int t = blockIdx.x * blockDim.x + threadIdx.x;
    if (t >= N_EDGES / 4) return;
    int4 s4 = esrc4[t];
    int4 d4 = edst4[t];
    int ss[4] = { s4.x, s4.y, s4.z, s4.w };
    int dd[4] = { d4.x, d4.y, d4.z, d4.w };
#pragma unroll
    for (int k = 0; k < 4; ++k) {
        float4 m = xe[ss[k]];
        float* base = summed + (size_t)dd[k] * 4;
        atomicAdd(base + 0, m.x);
        atomicAdd(base + 1, m.y);
        atomicAdd(base + 2, m.z);
        atomicAdd(base + 3, m.w);
        atomicAdd(counts + dd[k], 1.0f);
    }
}

// ---- Per-gun epilogue: mean + folded affine ----
__global__ void gun_kernel(const float4* __restrict__ summed, const float* __restrict__ counts,
                           const float* __restrict__ xg, const float* __restrict__ P,
                           float* __restrict__ out) {
    __shared__ float sP[48];
    if (threadIdx.x < 48) sP[threadIdx.x] = P[threadIdx.x];
    __syncthreads();
    int g = blockIdx.x * blockDim.x + threadIdx.x;
    if (g >= N_GUN) return;
    float4 s = summed[g];
    float cnt = counts[g];
    float inv = 1.0f / fmaxf(cnt, 1.0f);
    float m0 = s.x * inv, m1 = s.y * inv, m2 = s.z * inv, m3 = s.w * inv;
    float xv = xg[g];
    float res[OUTD];
#pragma unroll
    for (int o = 0; o < OUTD; ++o) {
        res[o] = m0 * sP[o] + m1 * sP[8 + o] + m2 * sP[16 + o] + m3 * sP[24 + o]
               + xv * sP[32 + o] + sP[40 + o];
    }
    float4* op = (float4*)(out + (size_t)g * OUTD);
    op[0] = make_float4(res[0], res[1], res[2], res[3]);
    op[1] = make_float4(res[4], res[5], res[6], res[7]);
}

extern "C" void kernel_launch(void* const* d_in, const int* in_sizes, int n_in,
                              void* d_out, int out_size, void* d_ws, size_t ws_size,
                              hipStream_t stream) {
    const float* x_enemy = (const float*)d_in[0];
    const float* x_gun   = (const float*)d_in[1];
    const int*   esrc    = (const int*)d_in[2];
    const int*   edst    = (const int*)d_in[3];
    const float* W_l     = (const float*)d_in[4];
    const float* b_l     = (const float*)d_in[5];
    const float* W_r     = (const float*)d_in[6];
    const float* W_fc    = (const float*)d_in[7];
    const float* b_fc    = (const float*)d_in[8];
    float* out = (float*)d_out;

    float* summed = (float*)d_ws;                      // N_GUN*4 floats = 16 MB
    float* counts = summed + (size_t)N_GUN * 4;        // N_GUN floats   =  4 MB
    float* P      = counts + N_GUN;                    // 48 floats

    hipMemsetAsync(d_ws, 0, ((size_t)N_GUN * 5 + 48) * sizeof(float), stream);

    prep_params<<<1, 64, 0, stream>>>(W_l, b_l, W_r, W_fc, b_fc, P);

    int edge_threads = N_EDGES / 4;                    // 4M threads
    edge_kernel<<<(edge_threads + 255) / 256, 256, 0, stream>>>(
        (const int4*)esrc, (const int4*)edst, (const float4*)x_enemy, summed, counts);

    gun_kernel<<<(N_GUN + 255) / 256, 256, 0, stream>>>(
        (const float4*)summed, counts, x_gun, P, out);
}

// Round 2
// 671.808 us; speedup vs baseline: 5.8402x; 5.8402x over previous
//
#include <hip/hip_runtime.h>

#define N_ENEMY 4000000
#define N_GUN   1000000
#define N_EDGES 16000000
#define HID     64
#define OUTD    8

#define GUNS_PER_BUCKET 1024
#define NB 977                   // ceil(1e6 / 1024)
#define NBLK 256                 // partition/hist blocks
#define CHUNK4 15625             // int4 loads per block (x4 = 62500 edges; 256*62500 = 16M)

// ---- Fold W_l@W_fc (4x8), W_r@W_fc (8), b_l@W_fc + b_fc (8) into P[48] ----
__global__ void prep_params(const float* __restrict__ W_l, const float* __restrict__ b_l,
                            const float* __restrict__ W_r, const float* __restrict__ W_fc,
                            const float* __restrict__ b_fc, float* __restrict__ P) {
    int o = threadIdx.x;
    if (o < OUTD) {
        float a0 = 0.f, a1 = 0.f, a2 = 0.f, a3 = 0.f, r = 0.f, c = 0.f;
        for (int h = 0; h < HID; ++h) {
            float w = W_fc[h * OUTD + o];
            a0 += W_l[0 * HID + h] * w;
            a1 += W_l[1 * HID + h] * w;
            a2 += W_l[2 * HID + h] * w;
            a3 += W_l[3 * HID + h] * w;
            r  += W_r[h] * w;
            c  += b_l[h] * w;
        }
        P[0 * OUTD + o] = a0;
        P[1 * OUTD + o] = a1;
        P[2 * OUTD + o] = a2;
        P[3 * OUTD + o] = a3;
        P[4 * OUTD + o] = r;
        P[5 * OUTD + o] = c + b_fc[o];
    }
}

// ---- Phase A: per-bucket histogram (LDS-aggregated) ----
__global__ void hist_kernel(const int4* __restrict__ edst4, unsigned int* __restrict__ hist) {
    __shared__ unsigned int lh[NB];
    for (int i = threadIdx.x; i < NB; i += 256) lh[i] = 0;
    __syncthreads();
    int base = blockIdx.x * CHUNK4;
    for (int i = threadIdx.x; i < CHUNK4; i += 256) {
        int4 d = edst4[base + i];
        atomicAdd(&lh[((unsigned)d.x) >> 10], 1u);
        atomicAdd(&lh[((unsigned)d.y) >> 10], 1u);
        atomicAdd(&lh[((unsigned)d.z) >> 10], 1u);
        atomicAdd(&lh[((unsigned)d.w) >> 10], 1u);
    }
    __syncthreads();
    for (int i = threadIdx.x; i < NB; i += 256)
        if (lh[i]) atomicAdd(&hist[i], lh[i]);
}

// ---- Phase B: exclusive scan of hist -> offsets[NB+1], cursor[NB] ----
__global__ void scan_kernel(const unsigned int* __restrict__ hist,
                            unsigned int* __restrict__ offsets,
                            unsigned int* __restrict__ cursor) {
    __shared__ unsigned int tmp[1024];
    int t = threadIdx.x;
    unsigned int v0 = (t < NB) ? hist[t] : 0u;
    tmp[t] = v0;
    __syncthreads();
    for (int d = 1; d < 1024; d <<= 1) {
        unsigned int v = (t >= d) ? tmp[t - d] : 0u;
        __syncthreads();
        tmp[t] += v;
        __syncthreads();
    }
    if (t < NB) {
        unsigned int excl = tmp[t] - v0;
        offsets[t] = excl;
        cursor[t]  = excl;
    }
    if (t == NB - 1) offsets[NB] = tmp[t];
}

// ---- Phase C: partition edges into bucket-contiguous payload ----
// payload word: (src << 10) | (dst & 1023)   [src < 2^22, fits exactly]
__global__ void scatter_kernel(const int4* __restrict__ esrc4, const int4* __restrict__ edst4,
                               unsigned int* __restrict__ cursor,
                               unsigned int* __restrict__ payload) {
    __shared__ unsigned int lh[NB];
    __shared__ unsigned int lbase[NB];
    for (int i = threadIdx.x; i < NB; i += 256) lh[i] = 0;
    __syncthreads();
    int base = blockIdx.x * CHUNK4;
    for (int i = threadIdx.x; i < CHUNK4; i += 256) {
        int4 d = edst4[base + i];
        atomicAdd(&lh[((unsigned)d.x) >> 10], 1u);
        atomicAdd(&lh[((unsigned)d.y) >> 10], 1u);
        atomicAdd(&lh[((unsigned)d.z) >> 10], 1u);
        atomicAdd(&lh[((unsigned)d.w) >> 10], 1u);
    }
    __syncthreads();
    for (int i = threadIdx.x; i < NB; i += 256) {
        unsigned int c = lh[i];
        lbase[i] = c ? atomicAdd(&cursor[i], c) : 0u;
        lh[i] = 0;   // reuse as running rank counter
    }
    __syncthreads();
    for (int i = threadIdx.x; i < CHUNK4; i += 256) {
        int4 s = esrc4[base + i];
        int4 d = edst4[base + i];
        int sv[4] = { s.x, s.y, s.z, s.w };
        int dv[4] = { d.x, d.y, d.z, d.w };
#pragma unroll
        for (int k = 0; k < 4; ++k) {
            unsigned int b = ((unsigned)dv[k]) >> 10;
            unsigned int r = atomicAdd(&lh[b], 1u);
            payload[lbase[b] + r] = (((unsigned)sv[k]) << 10) | (((unsigned)dv[k]) & 1023u);
        }
    }
}

// ---- Phase D: per-bucket aggregate in LDS + folded affine epilogue ----
__global__ void bucket_kernel(const unsigned int* __restrict__ offsets,
                              const unsigned int* __restrict__ payload,
                              const float4* __restrict__ xe,
                              const float* __restrict__ xg,
                              const float* __restrict__ P,
                              float* __restrict__ out) {
    __shared__ float s0[GUNS_PER_BUCKET], s1[GUNS_PER_BUCKET],
                     s2[GUNS_PER_BUCKET], s3[GUNS_PER_BUCKET];
    __shared__ unsigned int cc[GUNS_PER_BUCKET];
    __shared__ float sP[48];
    for (int i = threadIdx.x; i < GUNS_PER_BUCKET; i += 256) {
        s0[i] = 0.f; s1[i] = 0.f; s2[i] = 0.f; s3[i] = 0.f; cc[i] = 0u;
    }
    if (threadIdx.x < 48) sP[threadIdx.x] = P[threadIdx.x];
    __syncthreads();

    unsigned int start = offsets[blockIdx.x];
    unsigned int end   = offsets[blockIdx.x + 1];
    for (unsigned int i = start + threadIdx.x; i < end; i += 256) {
        unsigned int p = payload[i];
        unsigned int g = p & 1023u;
        float4 m = xe[p >> 10];
        atomicAdd(&s0[g], m.x);
        atomicAdd(&s1[g], m.y);
        atomicAdd(&s2[g], m.z);
        atomicAdd(&s3[g], m.w);
        atomicAdd(&cc[g], 1u);
    }
    __syncthreads();

    unsigned int gunBase = ((unsigned int)blockIdx.x) << 10;
    for (int g = threadIdx.x; g < GUNS_PER_BUCKET; g += 256) {
        unsigned int G = gunBase + g;
        if (G >= N_GUN) continue;
        float cnt = (float)cc[g];
        float inv = 1.0f / fmaxf(cnt, 1.0f);
        float m0 = s0[g] * inv, m1 = s1[g] * inv, m2 = s2[g] * inv, m3 = s3[g] * inv;
        float xv = xg[G];
        float res[OUTD];
#pragma unroll
        for (int o = 0; o < OUTD; ++o) {
            res[o] = m0 * sP[o] + m1 * sP[8 + o] + m2 * sP[16 + o] + m3 * sP[24 + o]
                   + xv * sP[32 + o] + sP[40 + o];
        }
        float4* op = (float4*)(out + (size_t)G * OUTD);
        op[0] = make_float4(res[0], res[1], res[2], res[3]);
        op[1] = make_float4(res[4], res[5], res[6], res[7]);
    }
}

// ================= fallback (round-1 path, needs only ~20 MB ws) =============
__global__ void edge_kernel(const int4* __restrict__ esrc4, const int4* __restrict__ edst4,
                            const float4* __restrict__ xe, float* __restrict__ summed,
                            float* __restrict__ counts) {
    int t = blockIdx.x * blockDim.x + threadIdx.x;
    if (t >= N_EDGES / 4) return;
    int4 s4 = esrc4[t];
    int4 d4 = edst4[t];
    int ss[4] = { s4.x, s4.y, s4.z, s4.w };
    int dd[4] = { d4.x, d4.y, d4.z, d4.w };
#pragma unroll
    for (int k = 0; k < 4; ++k) {
        float4 m = xe[ss[k]];
        float* base = summed + (size_t)dd[k] * 4;
        atomicAdd(base + 0, m.x);
        atomicAdd(base + 1, m.y);
        atomicAdd(base + 2, m.z);
        atomicAdd(base + 3, m.w);
        atomicAdd(counts + dd[k], 1.0f);
    }
}

__global__ void gun_kernel(const float4* __restrict__ summed, const float* __restrict__ counts,
                           const float* __restrict__ xg, const float* __restrict__ P,
                           float* __restrict__ out) {
    __shared__ float sP[48];
    if (threadIdx.x < 48) sP[threadIdx.x] = P[threadIdx.x];
    __syncthreads();
    int g = blockIdx.x * blockDim.x + threadIdx.x;
    if (g >= N_GUN) return;
    float4 s = summed[g];
    float cnt = counts[g];
    float inv = 1.0f / fmaxf(cnt, 1.0f);
    float m0 = s.x * inv, m1 = s.y * inv, m2 = s.z * inv, m3 = s.w * inv;
    float xv = xg[g];
    float res[OUTD];
#pragma unroll
    for (int o = 0; o < OUTD; ++o) {
        res[o] = m0 * sP[o] + m1 * sP[8 + o] + m2 * sP[16 + o] + m3 * sP[24 + o]
               + xv * sP[32 + o] + sP[40 + o];
    }
    float4* op = (float4*)(out + (size_t)g * OUTD);
    op[0] = make_float4(res[0], res[1], res[2], res[3]);
    op[1] = make_float4(res[4], res[5], res[6], res[7]);
}

extern "C" void kernel_launch(void* const* d_in, const int* in_sizes, int n_in,
                              void* d_out, int out_size, void* d_ws, size_t ws_size,
                              hipStream_t stream) {
    const float* x_enemy = (const float*)d_in[0];
    const float* x_gun   = (const float*)d_in[1];
    const int*   esrc    = (const int*)d_in[2];
    const int*   edst    = (const int*)d_in[3];
    const float* W_l     = (const float*)d_in[4];
    const float* b_l     = (const float*)d_in[5];
    const float* W_r     = (const float*)d_in[6];
    const float* W_fc    = (const float*)d_in[7];
    const float* b_fc    = (const float*)d_in[8];
    float* out = (float*)d_out;

    // ws layout (u32 units)
    const size_t PAYLOAD_OFF = 0;
    const size_t HIST_OFF    = (size_t)N_EDGES;            // 16,000,000
    const size_t OFFS_OFF    = HIST_OFF + NB;              // +977
    const size_t CURS_OFF    = OFFS_OFF + NB + 1;          // +978
    const size_t P_OFF       = CURS_OFF + NB;              // +977
    const size_t NEEDED      = (P_OFF + 48) * sizeof(unsigned int);

    if (ws_size >= NEEDED) {
        unsigned int* ws      = (unsigned int*)d_ws;
        unsigned int* payload = ws + PAYLOAD_OFF;
        unsigned int* hist    = ws + HIST_OFF;
        unsigned int* offsets = ws + OFFS_OFF;
        unsigned int* cursor  = ws + CURS_OFF;
        float*        P       = (float*)(ws + P_OFF);

        hipMemsetAsync(hist, 0, NB * sizeof(unsigned int), stream);
        prep_params<<<1, 64, 0, stream>>>(W_l, b_l, W_r, W_fc, b_fc, P);
        hist_kernel<<<NBLK, 256, 0, stream>>>((const int4*)edst, hist);
        scan_kernel<<<1, 1024, 0, stream>>>(hist, offsets, cursor);
        scatter_kernel<<<NBLK, 256, 0, stream>>>((const int4*)esrc, (const int4*)edst,
                                                 cursor, payload);
        bucket_kernel<<<NB, 256, 0, stream>>>(offsets, payload, (const float4*)x_enemy,
                                              x_gun, P, out);
    } else {
        // fallback: global-atomic path (20 MB ws)
        float* summed = (float*)d_ws;
        float* counts = summed + (size_t)N_GUN * 4;
        float* P      = counts + N_GUN;
        hipMemsetAsync(d_ws, 0, ((size_t)N_GUN * 5 + 48) * sizeof(float), stream);
        prep_params<<<1, 64, 0, stream>>>(W_l, b_l, W_r, W_fc, b_fc, P);
        int edge_threads = N_EDGES / 4;
        edge_kernel<<<(edge_threads + 255) / 256, 256, 0, stream>>>(
            (const int4*)esrc, (const int4*)edst, (const float4*)x_enemy, summed, counts);
        gun_kernel<<<(N_GUN + 255) / 256, 256, 0, stream>>>(
            (const float4*)summed, counts, x_gun, P, out);
    }
}